// Round 18
// baseline (232.014 us; speedup 1.0000x reference)
//
#include <hip/hip_runtime.h>
#include <cstddef>

#define BATCH 8
#define H_ 64
#define W_ 64
#define HW 4096
#define DIM 256
#define HEADS 8
#define KK 9
#define PADR 4356   // 66*66 padded pixels per batch

typedef unsigned short u16;
typedef unsigned int u32;
typedef __attribute__((ext_vector_type(8))) short short8;      // 8 bf16
typedef _Float16 __attribute__((ext_vector_type(8))) h8;       // 8 f16
typedef __attribute__((ext_vector_type(4))) float f32x4;

constexpr float kEps = 1e-5f;
constexpr float kInvSqrtD = 0.17677669529663687f;  // 32^-0.5

__device__ __forceinline__ u16 f2bf(float f){
  u32 u = __float_as_uint(f);
  u = (u + 0x7fffu + ((u >> 16) & 1u)) >> 16;
  return (u16)u;
}
__device__ __forceinline__ u16 f2h(float f){
  union { _Float16 h; u16 u; } cv;
  cv.h = (_Float16)f;                  // RNE f32->f16
  return cv.u;
}

__device__ __forceinline__ void gll16(const u16* g, u16* lds){
  __builtin_amdgcn_global_load_lds((const __attribute__((address_space(1))) u32*)g,
                                   (__attribute__((address_space(3))) u32*)lds, 16, 0, 0);
}

// ---------------------------------------------------------------------------
// Implicit-GEMM conv body v4: SAME 128x128xBK64 tile as the 5x-verified r10
// body, but SINGLE-buffered (32KB LDS) -> __launch_bounds__(256,4) = 4
// blocks/CU. Schedule = T3 minimum-2-phase:
//   [vmcnt(0)][bar][ds_read+MFMA][lgkm(0)][bar][stage ks+1]
// Rationale: blocks/CU was the decisive lever all session (1->2: 64->45us);
// the per-step drain is hidden by 3 other resident blocks (m114 overlap).
// Correctness argument identical to r7/r10 (verified): own vmcnt(0) before
// barrier => stage(ks) landed for all waves; lgkm(0)+barrier before
// stage(ks+1) => no wave still reads the buffer when overwritten.
// EPI: 0 BN+ReLU->f16 pad ; 1 (x+b)*S->f16 pad ; 2 x+b->f16 pad ;
//      3 BN+ReLU->f32 d_out (channel-major)
// ---------------------------------------------------------------------------
template<int CIN, int NTAP, int EPI>
__device__ __forceinline__ void conv_body(
    u16* smem, const int pix0, const int oc0,
    const u16* __restrict__ Act, const u16* __restrict__ Wt,
    const float* __restrict__ q0, const float* __restrict__ q1,
    const float* __restrict__ q2, const float* __restrict__ q3,
    const float* __restrict__ Smap,
    u16* __restrict__ Opad, float* __restrict__ Of32)
{
  constexpr int KCH = CIN / 64;
  constexpr int KSTEPS = NTAP * KCH;

  const int tid  = threadIdx.x;
  const int lane = tid & 63;
  const int wid  = tid >> 6;
  const int wm   = wid >> 1, wn = wid & 1;
  const int fr   = lane & 15;
  const int g    = lane >> 4;

  const int csw = ((tid & 7) ^ ((tid >> 3) & 7)) << 3;
  int a_src[4], b_src[4];
  #pragma unroll
  for (int q = 0; q < 4; ++q){
    const int r = q * 32 + (tid >> 3);
    const int pix = pix0 + r;
    const int b = pix >> 12, yx = pix & 4095;
    const int y = yx >> 6, x = yx & 63;
    a_src[q] = (b * PADR + (y + 1) * 66 + (x + 1)) * CIN + csw;
    b_src[q] = (oc0 + r) * CIN + csw;
  }

  f32x4 acc[4][4];
  #pragma unroll
  for (int m = 0; m < 4; ++m)
    #pragma unroll
    for (int n = 0; n < 4; ++n)
      acc[m][n] = (f32x4){0.f, 0.f, 0.f, 0.f};

  auto stage = [&](int ks){
    const int t  = (KCH == 1) ? ks : (ks / KCH);
    const int kb = (KCH == 1) ? 0  : ((ks % KCH) << 6);
    int ao = kb;
    if constexpr (NTAP == 9) ao += ((t / 3 - 1) * 66 + (t % 3 - 1)) * CIN;
    const int bo = t * (256 * CIN) + kb;
    u16* lA = smem + wid * 512;
    u16* lB = lA + 8192;
    #pragma unroll
    for (int q = 0; q < 4; ++q){
      gll16(Act + a_src[q] + ao, lA + q * 2048);
      gll16(Wt  + b_src[q] + bo, lB + q * 2048);
    }
  };

  stage(0);

  for (int ks = 0; ks < KSTEPS; ++ks){
    asm volatile("s_waitcnt vmcnt(0)" ::: "memory");
    __builtin_amdgcn_sched_barrier(0);
    __builtin_amdgcn_s_barrier();        // all waves' stage(ks) landed
    __builtin_amdgcn_sched_barrier(0);

    const u16* base = smem;
    h8 a[4][2], bb[4][2];
    #pragma unroll
    for (int m = 0; m < 4; ++m){
      const int R = wm * 64 + m * 16 + fr;
      #pragma unroll
      for (int kk = 0; kk < 2; ++kk)
        a[m][kk] = *(const h8*)&base[R * 64 + ((((kk << 2) + g) ^ (fr & 7)) << 3)];
    }
    #pragma unroll
    for (int n = 0; n < 4; ++n){
      const int R = wn * 64 + n * 16 + fr;
      #pragma unroll
      for (int kk = 0; kk < 2; ++kk)
        bb[n][kk] = *(const h8*)&base[8192 + R * 64 + ((((kk << 2) + g) ^ (fr & 7)) << 3)];
    }
    #pragma unroll
    for (int kk = 0; kk < 2; ++kk)
      #pragma unroll
      for (int n = 0; n < 4; ++n)
        #pragma unroll
        for (int m = 0; m < 4; ++m)
          acc[m][n] = __builtin_amdgcn_mfma_f32_16x16x32_f16(a[m][kk], bb[n][kk], acc[m][n], 0, 0, 0);

    __builtin_amdgcn_sched_barrier(0);
    asm volatile("s_waitcnt lgkmcnt(0)" ::: "memory");
    __builtin_amdgcn_sched_barrier(0);
    __builtin_amdgcn_s_barrier();        // all reads of the buffer done
    __builtin_amdgcn_sched_barrier(0);
    if (ks + 1 < KSTEPS) stage(ks + 1);  // safe to overwrite now
  }

  #pragma unroll
  for (int n = 0; n < 4; ++n){
    const int oc = oc0 + wn * 64 + n * 16 + fr;
    float sc, shv;
    if constexpr (EPI == 0 || EPI == 3){
      sc  = q0[oc] * rsqrtf(q3[oc] + kEps);
      shv = q1[oc] - q2[oc] * sc;
    } else {
      sc = 1.f; shv = q0[oc];
      (void)q1; (void)q2; (void)q3;
    }
    #pragma unroll
    for (int m = 0; m < 4; ++m){
      const int pixb = pix0 + wm * 64 + m * 16 + g * 4;
      f32x4 aa = acc[m][n];
      if constexpr (EPI == 3){
        const int b = pixb >> 12, yx = pixb & 4095;
        float4 o4;
        o4.x = fmaxf(fmaf(aa[0], sc, shv), 0.f);
        o4.y = fmaxf(fmaf(aa[1], sc, shv), 0.f);
        o4.z = fmaxf(fmaf(aa[2], sc, shv), 0.f);
        o4.w = fmaxf(fmaf(aa[3], sc, shv), 0.f);
        *(float4*)&Of32[((size_t)b * 256 + oc) * HW + yx] = o4;
      } else {
        #pragma unroll
        for (int r = 0; r < 4; ++r){
          const int pix = pixb + r;
          const int b = pix >> 12, yx = pix & 4095;
          const int y = yx >> 6, x = yx & 63;
          float v;
          if constexpr (EPI == 0)
            v = fmaxf(fmaf(aa[r], sc, shv), 0.f);
          else if constexpr (EPI == 1)
            v = (aa[r] + shv) * Smap[((size_t)b * HEADS + (oc >> 5)) * HW + yx];
          else  // EPI == 2
            v = aa[r] + shv;
          Opad[((size_t)b * PADR + (y + 1) * 66 + (x + 1)) * 256 + oc] = f2h(v);
        }
      }
    }
  }
}

template<int CIN, int NTAP, int EPI>
__global__ __launch_bounds__(256, 4) void gemm_conv(
    const u16* __restrict__ Act, const u16* __restrict__ Wt,
    const float* __restrict__ q0, const float* __restrict__ q1,
    const float* __restrict__ q2, const float* __restrict__ q3,
    const float* __restrict__ Smap,
    u16* __restrict__ Opad, float* __restrict__ Of32)
{
  __shared__ u16 smem[16384];   // 32KB: A+B single buffer -> 4 blocks/CU
  conv_body<CIN, NTAP, EPI>(smem, blockIdx.x * 128, blockIdx.y * 128,
                            Act, Wt, q0, q1, q2, q3, Smap, Opad, Of32);
}

// ---------------------------------------------------------------------------
// attn logits GEMM body (r5-verified): Lg[32768][72] = G @ Wcat^T + bias
// ---------------------------------------------------------------------------
__device__ __forceinline__ void attn_body(
    u16* smem, const int pix0,
    const u16* __restrict__ G, const u16* __restrict__ Wcat,
    const float* __restrict__ bfg, const float* __restrict__ bbg,
    float* __restrict__ Lg)
{
  const int tid  = threadIdx.x;
  const int lane = tid & 63;
  const int wid  = tid >> 6;

  const int ch8 = (tid & 3) * 8;
  int aoff[2];
  #pragma unroll
  for (int i = 0; i < 2; ++i){
    const int row = (tid + i * 256) >> 2;
    aoff[i] = (pix0 + row) * 512 + ch8;
  }

  f32x4 acc[2][5];
  #pragma unroll
  for (int m = 0; m < 2; ++m)
    #pragma unroll
    for (int n = 0; n < 5; ++n)
      acc[m][n] = (f32x4){0.f, 0.f, 0.f, 0.f};

  const int fr = lane & 15;
  const int fc = (lane >> 4) * 8;

  auto stage = [&](int ks, int bsel){
    u16* lA = smem + bsel * 4096 + wid * 512;
    gll16(G + aoff[0] + ks * 32, lA);
    gll16(G + aoff[1] + ks * 32, lA + 2048);
  };

  stage(0, 0);
  __syncthreads();

  for (int ks = 0; ks < 16; ++ks){
    const int bsel = ks & 1;
    if (ks + 1 < 16) stage(ks + 1, bsel ^ 1);

    const u16* base = smem + bsel * 4096;
    short8 a[2];
    #pragma unroll
    for (int m = 0; m < 2; ++m)
      a[m] = *(const short8*)&base[(wid * 32 + m * 16 + fr) * 32 + fc];
    #pragma unroll
    for (int n = 0; n < 5; ++n){
      short8 bfrag = *(const short8*)&Wcat[(size_t)(n * 16 + fr) * 512 + ks * 32 + fc];
      #pragma unroll
      for (int m = 0; m < 2; ++m)
        acc[m][n] = __builtin_amdgcn_mfma_f32_16x16x32_bf16(a[m], bfrag, acc[m][n], 0, 0, 0);
    }
    __syncthreads();
  }

  #pragma unroll
  for (int n = 0; n < 5; ++n){
    const int col = n * 16 + fr;
    if (col >= 72) continue;
    const float bias = bfg[col] - bbg[col];
    #pragma unroll
    for (int m = 0; m < 2; ++m)
      #pragma unroll
      for (int r = 0; r < 4; ++r){
        const int pix = pix0 + wid * 32 + m * 16 + (lane >> 4) * 4 + r;
        Lg[(size_t)pix * 72 + col] = acc[m][n][r] + bias;
      }
  }
}

// ---------------------------------------------------------------------------
// fused softmax+fold body (r5-verified)
// ---------------------------------------------------------------------------
__device__ __forceinline__ void fold_body(
    const int pb, const float* __restrict__ Lg, float* __restrict__ S)
{
  const int p  = pb * 256 + threadIdx.x;
  const int b  = p >> 12;
  const int yx = p & 4095;
  const int y  = yx >> 6, x = yx & 63;

  float s[8];
  #pragma unroll
  for (int h = 0; h < 8; ++h) s[h] = 0.f;

  #pragma unroll
  for (int i = 0; i < 3; ++i){
    const int ys = y + 1 - i;
    if (ys < 0 || ys >= H_) continue;
    #pragma unroll
    for (int j = 0; j < 3; ++j){
      const int xs = x + 1 - j;
      if (xs < 0 || xs >= W_) continue;
      const int pn = (b << 12) + ys * W_ + xs;
      const int k  = i * 3 + j;
      float d[72];
      #pragma unroll
      for (int q = 0; q < 18; ++q)
        *(float4*)&d[q * 4] = *(const float4*)&Lg[(size_t)pn * 72 + q * 4];
      #pragma unroll
      for (int h = 0; h < 8; ++h){
        float mx = d[h * 9];
        #pragma unroll
        for (int kk = 1; kk < 9; ++kk) mx = fmaxf(mx, d[h * 9 + kk]);
        float e[9], sum = 0.f;
        #pragma unroll
        for (int kk = 0; kk < 9; ++kk){
          e[kk] = __expf((d[h * 9 + kk] - mx) * kInvSqrtD);
          sum += e[kk];
        }
        s[h] += e[k] / sum;
      }
    }
  }
  #pragma unroll
  for (int h = 0; h < 8; ++h)
    S[(((size_t)b * HEADS + h) << 12) + yx] = s[h];
}

// ---------------------------------------------------------------------------
// pack_fgbg standalone (r5-verified fast form): grid (256,4)
// ---------------------------------------------------------------------------
__global__ __launch_bounds__(256) void pack_fgbg(
    const float* __restrict__ fg, const float* __restrict__ bg,
    u16* __restrict__ G)
{
  const int t = threadIdx.x;
  const int pix0 = blockIdx.x * 128;
  const int chg  = blockIdx.y * 128 + (t >> 6) * 32;
  const int pix  = pix0 + (t & 63) * 2;
  const int b = pix >> 12, yx = pix & 4095;

  u16 buf0[32], buf1[32];
  #pragma unroll
  for (int i = 0; i < 32; ++i){
    const int c = chg + i;
    const float* src = (c < 256)
        ? &fg[((size_t)b * 256 + c) * HW + yx]
        : &bg[((size_t)b * 256 + (c - 256)) * HW + yx];
    const float2 v = *(const float2*)src;
    buf0[i] = f2bf(v.x);
    buf1[i] = f2bf(v.y);
  }
  #pragma unroll
  for (int i = 0; i < 32; i += 8)
    *(short8*)&G[(size_t)pix * 512 + chg + i] = *(short8*)&buf0[i];
  #pragma unroll
  for (int i = 0; i < 32; i += 8)
    *(short8*)&G[(size_t)(pix + 1) * 512 + chg + i] = *(short8*)&buf1[i];
}

// ---------------------------------------------------------------------------
// pack_all (r8-verified form + slAB border zero): w1 576 | w2 2304 | w3 2304 |
// w4 2304 | wv 256 | wp 256 | wcat 160 | pack_x 128 | xpad-border 65 |
// slAB-zero 520 = 8873 blocks
// ---------------------------------------------------------------------------
__device__ __forceinline__ void packw_seg(const float* __restrict__ src,
    u16* __restrict__ dst, int CSH, int T, int idx)
{
  const int c  = idx & ((1 << CSH) - 1);
  const int to = idx >> CSH;           // t*256 + o
  const int o  = to & 255;
  const int t  = to >> 8;
  dst[idx] = f2h(src[(size_t)(((o << CSH) + c) * T) + t]);
}

__global__ __launch_bounds__(256) void pack_all(
    const float* __restrict__ w1, const float* __restrict__ w2,
    const float* __restrict__ w3, const float* __restrict__ w4,
    const float* __restrict__ Wv, const float* __restrict__ Wp,
    const float* __restrict__ Wfg, const float* __restrict__ Wbg,
    const float* __restrict__ x,
    u16* __restrict__ w1f, u16* __restrict__ w2f, u16* __restrict__ w3f,
    u16* __restrict__ w4f, u16* __restrict__ wvf, u16* __restrict__ wpf,
    u16* __restrict__ wcat, u16* __restrict__ xpad,
    u16* __restrict__ slA, u16* __restrict__ slB)
{
  const int bid = blockIdx.x;
  const int tid = threadIdx.x;

  if (bid < 576){                        // w1: C=64 T=9
    packw_seg(w1, w1f, 6, 9, bid * 256 + tid);
  } else if (bid < 2880){                // w2
    packw_seg(w2, w2f, 8, 9, (bid - 576) * 256 + tid);
  } else if (bid < 5184){                // w3
    packw_seg(w3, w3f, 8, 9, (bid - 2880) * 256 + tid);
  } else if (bid < 7488){                // w4
    packw_seg(w4, w4f, 8, 9, (bid - 5184) * 256 + tid);
  } else if (bid < 7744){                // Wv: T=1
    packw_seg(Wv, wvf, 8, 1, (bid - 7488) * 256 + tid);
  } else if (bid < 8000){                // Wp: T=1
    packw_seg(Wp, wpf, 8, 1, (bid - 7744) * 256 + tid);
  } else if (bid < 8160){                // wcat[80][512] bf16
    const int idx = (bid - 8000) * 256 + tid;
    const int o = idx >> 9, c = idx & 511;
    float v = 0.f;
    if (o < 72) v = (c < 256) ? Wfg[o * 256 + c] : -Wbg[o * 256 + (c - 256)];
    wcat[idx] = (o < 72) ? f2bf(v) : (u16)0;
  } else if (bid < 8288){                // pack x -> padded pixel-major f16
    const int p = (bid - 8160) * 256 + tid;
    const int b = p >> 12, yx = p & 4095;
    const int y = yx >> 6, xx = yx & 63;
    const size_t pr = ((size_t)b * PADR + (y + 1) * 66 + (xx + 1)) * 64;
    const float* xs = x + (size_t)b * 64 * HW + yx;
    #pragma unroll 8
    for (int c = 0; c < 64; c += 2){
      const u16 h0 = f2h(xs[(size_t)c * HW]);
      const u16 h1 = f2h(xs[(size_t)(c + 1) * HW]);
      *(u32*)&xpad[pr + c] = (u32)h0 | ((u32)h1 << 16);
    }
  } else if (bid < 8353){                // xpad border zero
    const int u = (bid - 8288) * 256 + tid;
    if (u >= 16640) return;
    const int b = u / 2080;
    const int r = u - b * 2080;
    const int pi = r >> 3;
    const int ch = (r & 7) * 8;
    int py, px;
    if (pi < 66){ py = 0; px = pi; }
    else if (pi < 132){ py = 65; px = pi - 66; }
    else { const int k = pi - 132; py = 1 + (k >> 1); px = (k & 1) * 65; }
    const short8 z = {0,0,0,0,0,0,0,0};
    *(short8*)&xpad[((size_t)b * PADR + py * 66 + px) * 64 + ch] = z;
  } else {                               // slA/slB border zero
    int u = (bid - 8353) * 256 + tid;
    u16* base = slA;
    if (u >= 66560){ base = slB; u -= 66560; }
    const int b = u / 8320;
    const int r = u - b * 8320;
    const int pi = r >> 5;
    const int ch = (r & 31) * 8;
    int py, px;
    if (pi < 66){ py = 0; px = pi; }
    else if (pi < 132){ py = 65; px = pi - 66; }
    else { const int k = pi - 132; py = 1 + (k >> 1); px = (k & 1) * 65; }
    const short8 z = {0,0,0,0,0,0,0,0};
    *(short8*)&base[((size_t)b * PADR + py * 66 + px) * 256 + ch] = z;
  }
}

// ---------------------------------------------------------------------------
// L2: attn_gemm (0..255, first — r15 measured-better) ∪ conv1 (256..767)
// ---------------------------------------------------------------------------
__global__ __launch_bounds__(256, 4) void conv1_attn_kernel(
    const u16* __restrict__ xpad, const u16* __restrict__ w1f,
    const float* __restrict__ g1, const float* __restrict__ b1,
    const float* __restrict__ m1, const float* __restrict__ v1,
    u16* __restrict__ slA,
    const u16* __restrict__ G, const u16* __restrict__ wcat,
    const float* __restrict__ bfg, const float* __restrict__ bbg,
    float* __restrict__ Lg)
{
  __shared__ u16 smem[16384];
  const int bid = blockIdx.x;
  if (bid < 256){
    attn_body(smem, bid * 128, G, wcat, bfg, bbg, Lg);
  } else {
    const int cb = bid - 256;
    conv_body<64, 9, 0>(smem, (cb & 255) * 128, (cb >> 8) * 128,
                        xpad, w1f, g1, b1, m1, v1, nullptr,
                        slA, nullptr);
  }
}

// ---------------------------------------------------------------------------
// L3: conv2 (0..511, first — r16 measured-better) ∪ softmax_fold (tail)
// ---------------------------------------------------------------------------
__global__ __launch_bounds__(256, 4) void conv2_fold_kernel(
    const u16* __restrict__ slA, const u16* __restrict__ w2f,
    const float* __restrict__ g2, const float* __restrict__ b2,
    const float* __restrict__ m2, const float* __restrict__ v2,
    u16* __restrict__ slB,
    const float* __restrict__ Lg, float* __restrict__ S)
{
  __shared__ u16 smem[16384];
  const int bid = blockIdx.x;
  if (bid < 512){
    conv_body<256, 9, 0>(smem, (bid & 255) * 128, (bid >> 8) * 128,
                         slA, w2f, g2, b2, m2, v2, nullptr,
                         slB, nullptr);
  } else {
    fold_body(bid - 512, Lg, S);
  }
}

// ---------------------------------------------------------------------------
extern "C" void kernel_launch(void* const* d_in, const int* in_sizes, int n_in,
                              void* d_out, int out_size, void* d_ws, size_t ws_size,
                              hipStream_t stream)
{
  const float* x   = (const float*)d_in[0];
  const float* fg  = (const float*)d_in[1];
  const float* bg  = (const float*)d_in[2];
  const float* w1  = (const float*)d_in[3];
  const float* g1  = (const float*)d_in[4];
  const float* b1  = (const float*)d_in[5];
  const float* m1  = (const float*)d_in[6];
  const float* v1  = (const float*)d_in[7];
  const float* w2  = (const float*)d_in[8];
  const float* g2  = (const float*)d_in[9];
  const float* b2  = (const float*)d_in[10];
  const float* m2  = (const float*)d_in[11];
  const float* v2  = (const float*)d_in[12];
  const float* Wv  = (const float*)d_in[13];
  const float* bv  = (const float*)d_in[14];
  const float* Wfg = (const float*)d_in[15];
  const float* bfg = (const float*)d_in[16];
  const float* Wbg = (const float*)d_in[17];
  const float* bbg = (const float*)d_in[18];
  const float* Wp  = (const float*)d_in[19];
  const float* bp  = (const float*)d_in[20];
  const float* w3  = (const float*)d_in[21];
  const float* g3  = (const float*)d_in[22];
  const float* b3  = (const float*)d_in[23];
  const float* m3  = (const float*)d_in[24];
  const float* v3  = (const float*)d_in[25];
  const float* w4  = (const float*)d_in[26];
  const float* g4  = (const float*)d_in[27];
  const float* b4  = (const float*)d_in[28];
  const float* m4  = (const float*)d_in[29];
  const float* v4  = (const float*)d_in[30];

  const size_t XB = (size_t)BATCH * PADR * 64 * 2;    // 4,460,544
  const size_t PB = (size_t)BATCH * PADR * 256 * 2;   // 17,842,176

  char* p = (char*)d_ws;
  u16* xpad = (u16*)p;             p += XB;
  u16* slA  = (u16*)p;             p += PB;
  u16* slB  = (u16*)p;             p += PB;
  u16* G    = (u16*)p;             p += (size_t)32768 * 512 * 2;  // 33.5MB
  u16* w1f  = (u16*)p; p += 294912;
  u16* w2f  = (u16*)p; p += 1179648;
  u16* w3f  = (u16*)p; p += 1179648;
  u16* w4f  = (u16*)p; p += 1179648;
  u16* wvf  = (u16*)p; p += 131072;
  u16* wpf  = (u16*)p; p += 131072;
  u16* wcat = (u16*)p;             p += 80 * 512 * 2;
  float* S    = (float*)p;         p += (size_t)BATCH * HEADS * HW * 4;
  float* Lg   = (float*)p;         p += (size_t)BATCH * HW * 72 * 4;

  const dim3 blk(256);

  // L0a: pack fg/bg -> G
  pack_fgbg<<<dim3(256, 4), blk, 0, stream>>>(fg, bg, G);

  // L0b: all weight/input packs + borders
  pack_all<<<dim3(8873), blk, 0, stream>>>(
      w1, w2, w3, w4, Wv, Wp, Wfg, Wbg, x,
      w1f, w2f, w3f, w4f, wvf, wpf, wcat, xpad, slA, slB);

  // L2: attn_gemm ∪ conv1
  conv1_attn_kernel<<<dim3(768), blk, 0, stream>>>(
      xpad, w1f, g1, b1, m1, v1, slA, G, wcat, bfg, bbg, Lg);

  // L3: conv2 ∪ softmax_fold
  conv2_fold_kernel<<<dim3(640), blk, 0, stream>>>(
      slA, w2f, g2, b2, m2, v2, slB, Lg, S);

  const dim3 ggrid(256, 2);
  // Wv + S-mul: slB -> slA (u = v*S)
  gemm_conv<256, 1, 1><<<ggrid, blk, 0, stream>>>(
      slB, wvf, bv, nullptr, nullptr, nullptr, S, slA, nullptr);
  // Wp: slA -> slB (o)
  gemm_conv<256, 1, 2><<<ggrid, blk, 0, stream>>>(
      slA, wpf, bp, nullptr, nullptr, nullptr, nullptr, slB, nullptr);
  // conv3: slB -> slA (h3)
  gemm_conv<256, 9, 0><<<ggrid, blk, 0, stream>>>(
      slB, w3f, g3, b3, m3, v3, nullptr, slA, nullptr);
  // conv4: slA -> d_out (f32 channel-major)
  gemm_conv<256, 9, 3><<<ggrid, blk, 0, stream>>>(
      slA, w4f, g4, b4, m4, v4, nullptr, nullptr, (float*)d_out);
}

// Round 19
// 227.980 us; speedup vs baseline: 1.0177x; 1.0177x over previous
//
#include <hip/hip_runtime.h>
#include <cstddef>

#define BATCH 8
#define H_ 64
#define W_ 64
#define HW 4096
#define DIM 256
#define HEADS 8
#define KK 9
#define PADR 4356   // 66*66 padded pixels per batch

typedef unsigned short u16;
typedef unsigned int u32;
typedef __attribute__((ext_vector_type(8))) short short8;      // 8 bf16
typedef _Float16 __attribute__((ext_vector_type(8))) h8;       // 8 f16
typedef __attribute__((ext_vector_type(4))) float f32x4;

constexpr float kEps = 1e-5f;
constexpr float kInvSqrtD = 0.17677669529663687f;  // 32^-0.5

__device__ __forceinline__ u16 f2bf(float f){
  u32 u = __float_as_uint(f);
  u = (u + 0x7fffu + ((u >> 16) & 1u)) >> 16;
  return (u16)u;
}
__device__ __forceinline__ u16 f2h(float f){
  union { _Float16 h; u16 u; } cv;
  cv.h = (_Float16)f;                  // RNE f32->f16
  return cv.u;
}

__device__ __forceinline__ void gll16(const u16* g, u16* lds){
  __builtin_amdgcn_global_load_lds((const __attribute__((address_space(1))) u32*)g,
                                   (__attribute__((address_space(3))) u32*)lds, 16, 0, 0);
}

// ---------------------------------------------------------------------------
// Implicit-GEMM conv body — r10 form (session optimum, verified 6x at 44.2us):
// BM=128 x BN=128, BK=64, 4 waves 64x64 out, A+B in 64KB LDS dbuf (2 blk/CU),
// XOR-swizzle via pre-swizzled gll source, counted-vmcnt 2-step pipeline.
// ~880 TF = the 2-barrier-structure ceiling. Design-space scan complete:
// beats {1blk BN=256, 1blk pipelined, 4blk BM=64, B-from-L2, 4blk single-buf}.
// EPI: 0 BN+ReLU->f16 pad ; 1 (x+b)*S->f16 pad ; 2 x+b->f16 pad ;
//      3 BN+ReLU->f32 d_out (channel-major)
// ---------------------------------------------------------------------------
template<int CIN, int NTAP, int EPI>
__device__ __forceinline__ void conv_body(
    u16* smem, const int pix0, const int oc0,
    const u16* __restrict__ Act, const u16* __restrict__ Wt,
    const float* __restrict__ q0, const float* __restrict__ q1,
    const float* __restrict__ q2, const float* __restrict__ q3,
    const float* __restrict__ Smap,
    u16* __restrict__ Opad, float* __restrict__ Of32)
{
  constexpr int KCH = CIN / 64;
  constexpr int KSTEPS = NTAP * KCH;

  const int tid  = threadIdx.x;
  const int lane = tid & 63;
  const int wid  = tid >> 6;
  const int wm   = wid >> 1, wn = wid & 1;
  const int fr   = lane & 15;
  const int g    = lane >> 4;

  const int csw = ((tid & 7) ^ ((tid >> 3) & 7)) << 3;
  int a_src[4], b_src[4];
  #pragma unroll
  for (int q = 0; q < 4; ++q){
    const int r = q * 32 + (tid >> 3);
    const int pix = pix0 + r;
    const int b = pix >> 12, yx = pix & 4095;
    const int y = yx >> 6, x = yx & 63;
    a_src[q] = (b * PADR + (y + 1) * 66 + (x + 1)) * CIN + csw;
    b_src[q] = (oc0 + r) * CIN + csw;
  }

  f32x4 acc[4][4];
  #pragma unroll
  for (int m = 0; m < 4; ++m)
    #pragma unroll
    for (int n = 0; n < 4; ++n)
      acc[m][n] = (f32x4){0.f, 0.f, 0.f, 0.f};

  auto stage = [&](int ks, int bsel){
    const int t  = (KCH == 1) ? ks : (ks / KCH);
    const int kb = (KCH == 1) ? 0  : ((ks % KCH) << 6);
    int ao = kb;
    if constexpr (NTAP == 9) ao += ((t / 3 - 1) * 66 + (t % 3 - 1)) * CIN;
    const int bo = t * (256 * CIN) + kb;
    u16* lA = smem + bsel * 16384 + wid * 512;
    u16* lB = lA + 8192;
    #pragma unroll
    for (int q = 0; q < 4; ++q){
      gll16(Act + a_src[q] + ao, lA + q * 2048);
      gll16(Wt  + b_src[q] + bo, lB + q * 2048);
    }
  };

  stage(0, 0);
  stage(1, 1);

  for (int ks = 0; ks < KSTEPS; ++ks){
    const int bsel = ks & 1;

    if (ks + 1 < KSTEPS) asm volatile("s_waitcnt vmcnt(8)" ::: "memory");
    else                 asm volatile("s_waitcnt vmcnt(0)" ::: "memory");
    __builtin_amdgcn_sched_barrier(0);
    __builtin_amdgcn_s_barrier();        // all waves' stage(ks) landed
    __builtin_amdgcn_sched_barrier(0);

    const u16* base = smem + bsel * 16384;
    h8 a[4][2], bb[4][2];
    #pragma unroll
    for (int m = 0; m < 4; ++m){
      const int R = wm * 64 + m * 16 + fr;
      #pragma unroll
      for (int kk = 0; kk < 2; ++kk)
        a[m][kk] = *(const h8*)&base[R * 64 + ((((kk << 2) + g) ^ (fr & 7)) << 3)];
    }
    #pragma unroll
    for (int n = 0; n < 4; ++n){
      const int R = wn * 64 + n * 16 + fr;
      #pragma unroll
      for (int kk = 0; kk < 2; ++kk)
        bb[n][kk] = *(const h8*)&base[8192 + R * 64 + ((((kk << 2) + g) ^ (fr & 7)) << 3)];
    }
    #pragma unroll
    for (int kk = 0; kk < 2; ++kk)
      #pragma unroll
      for (int n = 0; n < 4; ++n)
        #pragma unroll
        for (int m = 0; m < 4; ++m)
          acc[m][n] = __builtin_amdgcn_mfma_f32_16x16x32_f16(a[m][kk], bb[n][kk], acc[m][n], 0, 0, 0);

    __builtin_amdgcn_sched_barrier(0);
    asm volatile("s_waitcnt lgkmcnt(0)" ::: "memory");
    __builtin_amdgcn_sched_barrier(0);
    __builtin_amdgcn_s_barrier();        // all reads of buf[bsel] done
    __builtin_amdgcn_sched_barrier(0);
    if (ks + 2 < KSTEPS) stage(ks + 2, bsel);
  }

  #pragma unroll
  for (int n = 0; n < 4; ++n){
    const int oc = oc0 + wn * 64 + n * 16 + fr;
    float sc, shv;
    if constexpr (EPI == 0 || EPI == 3){
      sc  = q0[oc] * rsqrtf(q3[oc] + kEps);
      shv = q1[oc] - q2[oc] * sc;
    } else {
      sc = 1.f; shv = q0[oc];
      (void)q1; (void)q2; (void)q3;
    }
    #pragma unroll
    for (int m = 0; m < 4; ++m){
      const int pixb = pix0 + wm * 64 + m * 16 + g * 4;
      f32x4 aa = acc[m][n];
      if constexpr (EPI == 3){
        const int b = pixb >> 12, yx = pixb & 4095;
        float4 o4;
        o4.x = fmaxf(fmaf(aa[0], sc, shv), 0.f);
        o4.y = fmaxf(fmaf(aa[1], sc, shv), 0.f);
        o4.z = fmaxf(fmaf(aa[2], sc, shv), 0.f);
        o4.w = fmaxf(fmaf(aa[3], sc, shv), 0.f);
        *(float4*)&Of32[((size_t)b * 256 + oc) * HW + yx] = o4;
      } else {
        #pragma unroll
        for (int r = 0; r < 4; ++r){
          const int pix = pixb + r;
          const int b = pix >> 12, yx = pix & 4095;
          const int y = yx >> 6, x = yx & 63;
          float v;
          if constexpr (EPI == 0)
            v = fmaxf(fmaf(aa[r], sc, shv), 0.f);
          else if constexpr (EPI == 1)
            v = (aa[r] + shv) * Smap[((size_t)b * HEADS + (oc >> 5)) * HW + yx];
          else  // EPI == 2
            v = aa[r] + shv;
          Opad[((size_t)b * PADR + (y + 1) * 66 + (x + 1)) * 256 + oc] = f2h(v);
        }
      }
    }
  }
}

template<int CIN, int NTAP, int EPI>
__global__ __launch_bounds__(256, 2) void gemm_conv(
    const u16* __restrict__ Act, const u16* __restrict__ Wt,
    const float* __restrict__ q0, const float* __restrict__ q1,
    const float* __restrict__ q2, const float* __restrict__ q3,
    const float* __restrict__ Smap,
    u16* __restrict__ Opad, float* __restrict__ Of32)
{
  __shared__ u16 smem[32768];   // 64KB: A+B double-buffer
  conv_body<CIN, NTAP, EPI>(smem, blockIdx.x * 128, blockIdx.y * 128,
                            Act, Wt, q0, q1, q2, q3, Smap, Opad, Of32);
}

// ---------------------------------------------------------------------------
// attn logits GEMM body (r5-verified): Lg[32768][72] = G @ Wcat^T + bias
// ---------------------------------------------------------------------------
__device__ __forceinline__ void attn_body(
    u16* smem, const int pix0,
    const u16* __restrict__ G, const u16* __restrict__ Wcat,
    const float* __restrict__ bfg, const float* __restrict__ bbg,
    float* __restrict__ Lg)
{
  const int tid  = threadIdx.x;
  const int lane = tid & 63;
  const int wid  = tid >> 6;

  const int ch8 = (tid & 3) * 8;
  int aoff[2];
  #pragma unroll
  for (int i = 0; i < 2; ++i){
    const int row = (tid + i * 256) >> 2;
    aoff[i] = (pix0 + row) * 512 + ch8;
  }

  f32x4 acc[2][5];
  #pragma unroll
  for (int m = 0; m < 2; ++m)
    #pragma unroll
    for (int n = 0; n < 5; ++n)
      acc[m][n] = (f32x4){0.f, 0.f, 0.f, 0.f};

  const int fr = lane & 15;
  const int fc = (lane >> 4) * 8;

  auto stage = [&](int ks, int bsel){
    u16* lA = smem + bsel * 4096 + wid * 512;
    gll16(G + aoff[0] + ks * 32, lA);
    gll16(G + aoff[1] + ks * 32, lA + 2048);
  };

  stage(0, 0);
  __syncthreads();

  for (int ks = 0; ks < 16; ++ks){
    const int bsel = ks & 1;
    if (ks + 1 < 16) stage(ks + 1, bsel ^ 1);

    const u16* base = smem + bsel * 4096;
    short8 a[2];
    #pragma unroll
    for (int m = 0; m < 2; ++m)
      a[m] = *(const short8*)&base[(wid * 32 + m * 16 + fr) * 32 + fc];
    #pragma unroll
    for (int n = 0; n < 5; ++n){
      short8 bfrag = *(const short8*)&Wcat[(size_t)(n * 16 + fr) * 512 + ks * 32 + fc];
      #pragma unroll
      for (int m = 0; m < 2; ++m)
        acc[m][n] = __builtin_amdgcn_mfma_f32_16x16x32_bf16(a[m], bfrag, acc[m][n], 0, 0, 0);
    }
    __syncthreads();
  }

  #pragma unroll
  for (int n = 0; n < 5; ++n){
    const int col = n * 16 + fr;
    if (col >= 72) continue;
    const float bias = bfg[col] - bbg[col];
    #pragma unroll
    for (int m = 0; m < 2; ++m)
      #pragma unroll
      for (int r = 0; r < 4; ++r){
        const int pix = pix0 + wid * 32 + m * 16 + (lane >> 4) * 4 + r;
        Lg[(size_t)pix * 72 + col] = acc[m][n][r] + bias;
      }
  }
}

// ---------------------------------------------------------------------------
// fused softmax+fold body (r5-verified)
// ---------------------------------------------------------------------------
__device__ __forceinline__ void fold_body(
    const int pb, const float* __restrict__ Lg, float* __restrict__ S)
{
  const int p  = pb * 256 + threadIdx.x;
  const int b  = p >> 12;
  const int yx = p & 4095;
  const int y  = yx >> 6, x = yx & 63;

  float s[8];
  #pragma unroll
  for (int h = 0; h < 8; ++h) s[h] = 0.f;

  #pragma unroll
  for (int i = 0; i < 3; ++i){
    const int ys = y + 1 - i;
    if (ys < 0 || ys >= H_) continue;
    #pragma unroll
    for (int j = 0; j < 3; ++j){
      const int xs = x + 1 - j;
      if (xs < 0 || xs >= W_) continue;
      const int pn = (b << 12) + ys * W_ + xs;
      const int k  = i * 3 + j;
      float d[72];
      #pragma unroll
      for (int q = 0; q < 18; ++q)
        *(float4*)&d[q * 4] = *(const float4*)&Lg[(size_t)pn * 72 + q * 4];
      #pragma unroll
      for (int h = 0; h < 8; ++h){
        float mx = d[h * 9];
        #pragma unroll
        for (int kk = 1; kk < 9; ++kk) mx = fmaxf(mx, d[h * 9 + kk]);
        float e[9], sum = 0.f;
        #pragma unroll
        for (int kk = 0; kk < 9; ++kk){
          e[kk] = __expf((d[h * 9 + kk] - mx) * kInvSqrtD);
          sum += e[kk];
        }
        s[h] += e[k] / sum;
      }
    }
  }
  #pragma unroll
  for (int h = 0; h < 8; ++h)
    S[(((size_t)b * HEADS + h) << 12) + yx] = s[h];
}

// ---------------------------------------------------------------------------
// pack_fgbg standalone (r5-verified fast form): grid (256,4)
// ---------------------------------------------------------------------------
__global__ __launch_bounds__(256) void pack_fgbg(
    const float* __restrict__ fg, const float* __restrict__ bg,
    u16* __restrict__ G)
{
  const int t = threadIdx.x;
  const int pix0 = blockIdx.x * 128;
  const int chg  = blockIdx.y * 128 + (t >> 6) * 32;
  const int pix  = pix0 + (t & 63) * 2;
  const int b = pix >> 12, yx = pix & 4095;

  u16 buf0[32], buf1[32];
  #pragma unroll
  for (int i = 0; i < 32; ++i){
    const int c = chg + i;
    const float* src = (c < 256)
        ? &fg[((size_t)b * 256 + c) * HW + yx]
        : &bg[((size_t)b * 256 + (c - 256)) * HW + yx];
    const float2 v = *(const float2*)src;
    buf0[i] = f2bf(v.x);
    buf1[i] = f2bf(v.y);
  }
  #pragma unroll
  for (int i = 0; i < 32; i += 8)
    *(short8*)&G[(size_t)pix * 512 + chg + i] = *(short8*)&buf0[i];
  #pragma unroll
  for (int i = 0; i < 32; i += 8)
    *(short8*)&G[(size_t)(pix + 1) * 512 + chg + i] = *(short8*)&buf1[i];
}

// ---------------------------------------------------------------------------
// pack_all (r8-verified form + slAB border zero): w1 576 | w2 2304 | w3 2304 |
// w4 2304 | wv 256 | wp 256 | wcat 160 | pack_x 128 | xpad-border 65 |
// slAB-zero 520 = 8873 blocks
// ---------------------------------------------------------------------------
__device__ __forceinline__ void packw_seg(const float* __restrict__ src,
    u16* __restrict__ dst, int CSH, int T, int idx)
{
  const int c  = idx & ((1 << CSH) - 1);
  const int to = idx >> CSH;           // t*256 + o
  const int o  = to & 255;
  const int t  = to >> 8;
  dst[idx] = f2h(src[(size_t)(((o << CSH) + c) * T) + t]);
}

__global__ __launch_bounds__(256) void pack_all(
    const float* __restrict__ w1, const float* __restrict__ w2,
    const float* __restrict__ w3, const float* __restrict__ w4,
    const float* __restrict__ Wv, const float* __restrict__ Wp,
    const float* __restrict__ Wfg, const float* __restrict__ Wbg,
    const float* __restrict__ x,
    u16* __restrict__ w1f, u16* __restrict__ w2f, u16* __restrict__ w3f,
    u16* __restrict__ w4f, u16* __restrict__ wvf, u16* __restrict__ wpf,
    u16* __restrict__ wcat, u16* __restrict__ xpad,
    u16* __restrict__ slA, u16* __restrict__ slB)
{
  const int bid = blockIdx.x;
  const int tid = threadIdx.x;

  if (bid < 576){                        // w1: C=64 T=9
    packw_seg(w1, w1f, 6, 9, bid * 256 + tid);
  } else if (bid < 2880){                // w2
    packw_seg(w2, w2f, 8, 9, (bid - 576) * 256 + tid);
  } else if (bid < 5184){                // w3
    packw_seg(w3, w3f, 8, 9, (bid - 2880) * 256 + tid);
  } else if (bid < 7488){                // w4
    packw_seg(w4, w4f, 8, 9, (bid - 5184) * 256 + tid);
  } else if (bid < 7744){                // Wv: T=1
    packw_seg(Wv, wvf, 8, 1, (bid - 7488) * 256 + tid);
  } else if (bid < 8000){                // Wp: T=1
    packw_seg(Wp, wpf, 8, 1, (bid - 7744) * 256 + tid);
  } else if (bid < 8160){                // wcat[80][512] bf16
    const int idx = (bid - 8000) * 256 + tid;
    const int o = idx >> 9, c = idx & 511;
    float v = 0.f;
    if (o < 72) v = (c < 256) ? Wfg[o * 256 + c] : -Wbg[o * 256 + (c - 256)];
    wcat[idx] = (o < 72) ? f2bf(v) : (u16)0;
  } else if (bid < 8288){                // pack x -> padded pixel-major f16
    const int p = (bid - 8160) * 256 + tid;
    const int b = p >> 12, yx = p & 4095;
    const int y = yx >> 6, xx = yx & 63;
    const size_t pr = ((size_t)b * PADR + (y + 1) * 66 + (xx + 1)) * 64;
    const float* xs = x + (size_t)b * 64 * HW + yx;
    #pragma unroll 8
    for (int c = 0; c < 64; c += 2){
      const u16 h0 = f2h(xs[(size_t)c * HW]);
      const u16 h1 = f2h(xs[(size_t)(c + 1) * HW]);
      *(u32*)&xpad[pr + c] = (u32)h0 | ((u32)h1 << 16);
    }
  } else if (bid < 8353){                // xpad border zero
    const int u = (bid - 8288) * 256 + tid;
    if (u >= 16640) return;
    const int b = u / 2080;
    const int r = u - b * 2080;
    const int pi = r >> 3;
    const int ch = (r & 7) * 8;
    int py, px;
    if (pi < 66){ py = 0; px = pi; }
    else if (pi < 132){ py = 65; px = pi - 66; }
    else { const int k = pi - 132; py = 1 + (k >> 1); px = (k & 1) * 65; }
    const short8 z = {0,0,0,0,0,0,0,0};
    *(short8*)&xpad[((size_t)b * PADR + py * 66 + px) * 64 + ch] = z;
  } else {                               // slA/slB border zero
    int u = (bid - 8353) * 256 + tid;
    u16* base = slA;
    if (u >= 66560){ base = slB; u -= 66560; }
    const int b = u / 8320;
    const int r = u - b * 8320;
    const int pi = r >> 5;
    const int ch = (r & 31) * 8;
    int py, px;
    if (pi < 66){ py = 0; px = pi; }
    else if (pi < 132){ py = 65; px = pi - 66; }
    else { const int k = pi - 132; py = 1 + (k >> 1); px = (k & 1) * 65; }
    const short8 z = {0,0,0,0,0,0,0,0};
    *(short8*)&base[((size_t)b * PADR + py * 66 + px) * 256 + ch] = z;
  }
}

// ---------------------------------------------------------------------------
// L2: attn_gemm (0..255, first — r15/r17 measured-better) ∪ conv1 (256..767)
// ---------------------------------------------------------------------------
__global__ __launch_bounds__(256, 2) void conv1_attn_kernel(
    const u16* __restrict__ xpad, const u16* __restrict__ w1f,
    const float* __restrict__ g1, const float* __restrict__ b1,
    const float* __restrict__ m1, const float* __restrict__ v1,
    u16* __restrict__ slA,
    const u16* __restrict__ G, const u16* __restrict__ wcat,
    const float* __restrict__ bfg, const float* __restrict__ bbg,
    float* __restrict__ Lg)
{
  __shared__ u16 smem[32768];
  const int bid = blockIdx.x;
  if (bid < 256){
    attn_body(smem, bid * 128, G, wcat, bfg, bbg, Lg);
  } else {
    const int cb = bid - 256;
    conv_body<64, 9, 0>(smem, (cb & 255) * 128, (cb >> 8) * 128,
                        xpad, w1f, g1, b1, m1, v1, nullptr,
                        slA, nullptr);
  }
}

// ---------------------------------------------------------------------------
// L3: conv2 (0..511, first — r16/r17 measured-better) ∪ softmax_fold (tail)
// ---------------------------------------------------------------------------
__global__ __launch_bounds__(256, 2) void conv2_fold_kernel(
    const u16* __restrict__ slA, const u16* __restrict__ w2f,
    const float* __restrict__ g2, const float* __restrict__ b2,
    const float* __restrict__ m2, const float* __restrict__ v2,
    u16* __restrict__ slB,
    const float* __restrict__ Lg, float* __restrict__ S)
{
  __shared__ u16 smem[32768];
  const int bid = blockIdx.x;
  if (bid < 512){
    conv_body<256, 9, 0>(smem, (bid & 255) * 128, (bid >> 8) * 128,
                         slA, w2f, g2, b2, m2, v2, nullptr,
                         slB, nullptr);
  } else {
    fold_body(bid - 512, Lg, S);
  }
}

// ---------------------------------------------------------------------------
extern "C" void kernel_launch(void* const* d_in, const int* in_sizes, int n_in,
                              void* d_out, int out_size, void* d_ws, size_t ws_size,
                              hipStream_t stream)
{
  const float* x   = (const float*)d_in[0];
  const float* fg  = (const float*)d_in[1];
  const float* bg  = (const float*)d_in[2];
  const float* w1  = (const float*)d_in[3];
  const float* g1  = (const float*)d_in[4];
  const float* b1  = (const float*)d_in[5];
  const float* m1  = (const float*)d_in[6];
  const float* v1  = (const float*)d_in[7];
  const float* w2  = (const float*)d_in[8];
  const float* g2  = (const float*)d_in[9];
  const float* b2  = (const float*)d_in[10];
  const float* m2  = (const float*)d_in[11];
  const float* v2  = (const float*)d_in[12];
  const float* Wv  = (const float*)d_in[13];
  const float* bv  = (const float*)d_in[14];
  const float* Wfg = (const float*)d_in[15];
  const float* bfg = (const float*)d_in[16];
  const float* Wbg = (const float*)d_in[17];
  const float* bbg = (const float*)d_in[18];
  const float* Wp  = (const float*)d_in[19];
  const float* bp  = (const float*)d_in[20];
  const float* w3  = (const float*)d_in[21];
  const float* g3  = (const float*)d_in[22];
  const float* b3  = (const float*)d_in[23];
  const float* m3  = (const float*)d_in[24];
  const float* v3  = (const float*)d_in[25];
  const float* w4  = (const float*)d_in[26];
  const float* g4  = (const float*)d_in[27];
  const float* b4  = (const float*)d_in[28];
  const float* m4  = (const float*)d_in[29];
  const float* v4  = (const float*)d_in[30];

  const size_t XB = (size_t)BATCH * PADR * 64 * 2;    // 4,460,544
  const size_t PB = (size_t)BATCH * PADR * 256 * 2;   // 17,842,176

  char* p = (char*)d_ws;
  u16* xpad = (u16*)p;             p += XB;
  u16* slA  = (u16*)p;             p += PB;
  u16* slB  = (u16*)p;             p += PB;
  u16* G    = (u16*)p;             p += (size_t)32768 * 512 * 2;  // 33.5MB
  u16* w1f  = (u16*)p; p += 294912;
  u16* w2f  = (u16*)p; p += 1179648;
  u16* w3f  = (u16*)p; p += 1179648;
  u16* w4f  = (u16*)p; p += 1179648;
  u16* wvf  = (u16*)p; p += 131072;
  u16* wpf  = (u16*)p; p += 131072;
  u16* wcat = (u16*)p;             p += 80 * 512 * 2;
  float* S    = (float*)p;         p += (size_t)BATCH * HEADS * HW * 4;
  float* Lg   = (float*)p;         p += (size_t)BATCH * HW * 72 * 4;

  const dim3 blk(256);

  // L0a: pack fg/bg -> G
  pack_fgbg<<<dim3(256, 4), blk, 0, stream>>>(fg, bg, G);

  // L0b: all weight/input packs + borders
  pack_all<<<dim3(8873), blk, 0, stream>>>(
      w1, w2, w3, w4, Wv, Wp, Wfg, Wbg, x,
      w1f, w2f, w3f, w4f, wvf, wpf, wcat, xpad, slA, slB);

  // L2: attn_gemm ∪ conv1 (attn first)
  conv1_attn_kernel<<<dim3(768), blk, 0, stream>>>(
      xpad, w1f, g1, b1, m1, v1, slA, G, wcat, bfg, bbg, Lg);

  // L3: conv2 ∪ softmax_fold (conv first)
  conv2_fold_kernel<<<dim3(640), blk, 0, stream>>>(
      slA, w2f, g2, b2, m2, v2, slB, Lg, S);

  const dim3 ggrid(256, 2);
  // Wv + S-mul: slB -> slA (u = v*S)
  gemm_conv<256, 1, 1><<<ggrid, blk, 0, stream>>>(
      slB, wvf, bv, nullptr, nullptr, nullptr, S, slA, nullptr);
  // Wp: slA -> slB (o)
  gemm_conv<256, 1, 2><<<ggrid, blk, 0, stream>>>(
      slA, wpf, bp, nullptr, nullptr, nullptr, nullptr, slB, nullptr);
  // conv3: slB -> slA (h3)
  gemm_conv<256, 9, 0><<<ggrid, blk, 0, stream>>>(
      slB, w3f, g3, b3, m3, v3, nullptr, slA, nullptr);
  // conv4: slA -> d_out (f32 channel-major)
  gemm_conv<256, 9, 3><<<ggrid, blk, 0, stream>>>(
      slA, w4f, g4, b4, m4, v4, nullptr, nullptr, (float*)d_out);
}

// Round 20
// 224.575 us; speedup vs baseline: 1.0331x; 1.0152x over previous
//
#include <hip/hip_runtime.h>
#include <cstddef>

#define BATCH 8
#define H_ 64
#define W_ 64
#define HW 4096
#define DIM 256
#define HEADS 8
#define KK 9
#define PADR 4356   // 66*66 padded pixels per batch

typedef unsigned short u16;
typedef unsigned int u32;
typedef __attribute__((ext_vector_type(8))) short short8;      // 8 bf16
typedef _Float16 __attribute__((ext_vector_type(8))) h8;       // 8 f16
typedef __attribute__((ext_vector_type(4))) float f32x4;

constexpr float kEps = 1e-5f;
constexpr float kInvSqrtD = 0.17677669529663687f;  // 32^-0.5

__device__ __forceinline__ u16 f2bf(float f){
  u32 u = __float_as_uint(f);
  u = (u + 0x7fffu + ((u >> 16) & 1u)) >> 16;
  return (u16)u;
}
__device__ __forceinline__ u16 f2h(float f){
  union { _Float16 h; u16 u; } cv;
  cv.h = (_Float16)f;                  // RNE f32->f16
  return cv.u;
}

__device__ __forceinline__ void gll16(const u16* g, u16* lds){
  __builtin_amdgcn_global_load_lds((const __attribute__((address_space(1))) u32*)g,
                                   (__attribute__((address_space(3))) u32*)lds, 16, 0, 0);
}

// ---------------------------------------------------------------------------
// Implicit-GEMM conv body — r10 form (session optimum, verified 7x at 44.2us):
// BM=128 x BN=128, BK=64, 4 waves 64x64 out, A+B in 64KB LDS dbuf (2 blk/CU),
// XOR-swizzle via pre-swizzled gll source, counted-vmcnt 2-step pipeline.
// ~880 TF = the 2-barrier-structure ceiling. Design-space scan complete.
// EPI: 0 BN+ReLU->f16 pad ; 1 (x+b)*S->f16 pad ; 2 x+b->f16 pad ;
//      3 BN+ReLU->f32 d_out (channel-major)
// ---------------------------------------------------------------------------
template<int CIN, int NTAP, int EPI>
__device__ __forceinline__ void conv_body(
    u16* smem, const int pix0, const int oc0,
    const u16* __restrict__ Act, const u16* __restrict__ Wt,
    const float* __restrict__ q0, const float* __restrict__ q1,
    const float* __restrict__ q2, const float* __restrict__ q3,
    const float* __restrict__ Smap,
    u16* __restrict__ Opad, float* __restrict__ Of32)
{
  constexpr int KCH = CIN / 64;
  constexpr int KSTEPS = NTAP * KCH;

  const int tid  = threadIdx.x;
  const int lane = tid & 63;
  const int wid  = tid >> 6;
  const int wm   = wid >> 1, wn = wid & 1;
  const int fr   = lane & 15;
  const int g    = lane >> 4;

  const int csw = ((tid & 7) ^ ((tid >> 3) & 7)) << 3;
  int a_src[4], b_src[4];
  #pragma unroll
  for (int q = 0; q < 4; ++q){
    const int r = q * 32 + (tid >> 3);
    const int pix = pix0 + r;
    const int b = pix >> 12, yx = pix & 4095;
    const int y = yx >> 6, x = yx & 63;
    a_src[q] = (b * PADR + (y + 1) * 66 + (x + 1)) * CIN + csw;
    b_src[q] = (oc0 + r) * CIN + csw;
  }

  f32x4 acc[4][4];
  #pragma unroll
  for (int m = 0; m < 4; ++m)
    #pragma unroll
    for (int n = 0; n < 4; ++n)
      acc[m][n] = (f32x4){0.f, 0.f, 0.f, 0.f};

  auto stage = [&](int ks, int bsel){
    const int t  = (KCH == 1) ? ks : (ks / KCH);
    const int kb = (KCH == 1) ? 0  : ((ks % KCH) << 6);
    int ao = kb;
    if constexpr (NTAP == 9) ao += ((t / 3 - 1) * 66 + (t % 3 - 1)) * CIN;
    const int bo = t * (256 * CIN) + kb;
    u16* lA = smem + bsel * 16384 + wid * 512;
    u16* lB = lA + 8192;
    #pragma unroll
    for (int q = 0; q < 4; ++q){
      gll16(Act + a_src[q] + ao, lA + q * 2048);
      gll16(Wt  + b_src[q] + bo, lB + q * 2048);
    }
  };

  stage(0, 0);
  stage(1, 1);

  for (int ks = 0; ks < KSTEPS; ++ks){
    const int bsel = ks & 1;

    if (ks + 1 < KSTEPS) asm volatile("s_waitcnt vmcnt(8)" ::: "memory");
    else                 asm volatile("s_waitcnt vmcnt(0)" ::: "memory");
    __builtin_amdgcn_sched_barrier(0);
    __builtin_amdgcn_s_barrier();        // all waves' stage(ks) landed
    __builtin_amdgcn_sched_barrier(0);

    const u16* base = smem + bsel * 16384;
    h8 a[4][2], bb[4][2];
    #pragma unroll
    for (int m = 0; m < 4; ++m){
      const int R = wm * 64 + m * 16 + fr;
      #pragma unroll
      for (int kk = 0; kk < 2; ++kk)
        a[m][kk] = *(const h8*)&base[R * 64 + ((((kk << 2) + g) ^ (fr & 7)) << 3)];
    }
    #pragma unroll
    for (int n = 0; n < 4; ++n){
      const int R = wn * 64 + n * 16 + fr;
      #pragma unroll
      for (int kk = 0; kk < 2; ++kk)
        bb[n][kk] = *(const h8*)&base[8192 + R * 64 + ((((kk << 2) + g) ^ (fr & 7)) << 3)];
    }
    #pragma unroll
    for (int kk = 0; kk < 2; ++kk)
      #pragma unroll
      for (int n = 0; n < 4; ++n)
        #pragma unroll
        for (int m = 0; m < 4; ++m)
          acc[m][n] = __builtin_amdgcn_mfma_f32_16x16x32_f16(a[m][kk], bb[n][kk], acc[m][n], 0, 0, 0);

    __builtin_amdgcn_sched_barrier(0);
    asm volatile("s_waitcnt lgkmcnt(0)" ::: "memory");
    __builtin_amdgcn_sched_barrier(0);
    __builtin_amdgcn_s_barrier();        // all reads of buf[bsel] done
    __builtin_amdgcn_sched_barrier(0);
    if (ks + 2 < KSTEPS) stage(ks + 2, bsel);
  }

  #pragma unroll
  for (int n = 0; n < 4; ++n){
    const int oc = oc0 + wn * 64 + n * 16 + fr;
    float sc, shv;
    if constexpr (EPI == 0 || EPI == 3){
      sc  = q0[oc] * rsqrtf(q3[oc] + kEps);
      shv = q1[oc] - q2[oc] * sc;
    } else {
      sc = 1.f; shv = q0[oc];
      (void)q1; (void)q2; (void)q3;
    }
    #pragma unroll
    for (int m = 0; m < 4; ++m){
      const int pixb = pix0 + wm * 64 + m * 16 + g * 4;
      f32x4 aa = acc[m][n];
      if constexpr (EPI == 3){
        const int b = pixb >> 12, yx = pixb & 4095;
        float4 o4;
        o4.x = fmaxf(fmaf(aa[0], sc, shv), 0.f);
        o4.y = fmaxf(fmaf(aa[1], sc, shv), 0.f);
        o4.z = fmaxf(fmaf(aa[2], sc, shv), 0.f);
        o4.w = fmaxf(fmaf(aa[3], sc, shv), 0.f);
        *(float4*)&Of32[((size_t)b * 256 + oc) * HW + yx] = o4;
      } else {
        #pragma unroll
        for (int r = 0; r < 4; ++r){
          const int pix = pixb + r;
          const int b = pix >> 12, yx = pix & 4095;
          const int y = yx >> 6, x = yx & 63;
          float v;
          if constexpr (EPI == 0)
            v = fmaxf(fmaf(aa[r], sc, shv), 0.f);
          else if constexpr (EPI == 1)
            v = (aa[r] + shv) * Smap[((size_t)b * HEADS + (oc >> 5)) * HW + yx];
          else  // EPI == 2
            v = aa[r] + shv;
          Opad[((size_t)b * PADR + (y + 1) * 66 + (x + 1)) * 256 + oc] = f2h(v);
        }
      }
    }
  }
}

template<int CIN, int NTAP, int EPI>
__global__ __launch_bounds__(256, 2) void gemm_conv(
    const u16* __restrict__ Act, const u16* __restrict__ Wt,
    const float* __restrict__ q0, const float* __restrict__ q1,
    const float* __restrict__ q2, const float* __restrict__ q3,
    const float* __restrict__ Smap,
    u16* __restrict__ Opad, float* __restrict__ Of32)
{
  __shared__ u16 smem[32768];   // 64KB: A+B double-buffer
  conv_body<CIN, NTAP, EPI>(smem, blockIdx.x * 128, blockIdx.y * 128,
                            Act, Wt, q0, q1, q2, q3, Smap, Opad, Of32);
}

// ---------------------------------------------------------------------------
// attn logits GEMM body (r5-verified): Lg[32768][72] = G @ Wcat^T + bias
// ---------------------------------------------------------------------------
__device__ __forceinline__ void attn_body(
    u16* smem, const int pix0,
    const u16* __restrict__ G, const u16* __restrict__ Wcat,
    const float* __restrict__ bfg, const float* __restrict__ bbg,
    float* __restrict__ Lg)
{
  const int tid  = threadIdx.x;
  const int lane = tid & 63;
  const int wid  = tid >> 6;

  const int ch8 = (tid & 3) * 8;
  int aoff[2];
  #pragma unroll
  for (int i = 0; i < 2; ++i){
    const int row = (tid + i * 256) >> 2;
    aoff[i] = (pix0 + row) * 512 + ch8;
  }

  f32x4 acc[2][5];
  #pragma unroll
  for (int m = 0; m < 2; ++m)
    #pragma unroll
    for (int n = 0; n < 5; ++n)
      acc[m][n] = (f32x4){0.f, 0.f, 0.f, 0.f};

  const int fr = lane & 15;
  const int fc = (lane >> 4) * 8;

  auto stage = [&](int ks, int bsel){
    u16* lA = smem + bsel * 4096 + wid * 512;
    gll16(G + aoff[0] + ks * 32, lA);
    gll16(G + aoff[1] + ks * 32, lA + 2048);
  };

  stage(0, 0);
  __syncthreads();

  for (int ks = 0; ks < 16; ++ks){
    const int bsel = ks & 1;
    if (ks + 1 < 16) stage(ks + 1, bsel ^ 1);

    const u16* base = smem + bsel * 4096;
    short8 a[2];
    #pragma unroll
    for (int m = 0; m < 2; ++m)
      a[m] = *(const short8*)&base[(wid * 32 + m * 16 + fr) * 32 + fc];
    #pragma unroll
    for (int n = 0; n < 5; ++n){
      short8 bfrag = *(const short8*)&Wcat[(size_t)(n * 16 + fr) * 512 + ks * 32 + fc];
      #pragma unroll
      for (int m = 0; m < 2; ++m)
        acc[m][n] = __builtin_amdgcn_mfma_f32_16x16x32_bf16(a[m], bfrag, acc[m][n], 0, 0, 0);
    }
    __syncthreads();
  }

  #pragma unroll
  for (int n = 0; n < 5; ++n){
    const int col = n * 16 + fr;
    if (col >= 72) continue;
    const float bias = bfg[col] - bbg[col];
    #pragma unroll
    for (int m = 0; m < 2; ++m)
      #pragma unroll
      for (int r = 0; r < 4; ++r){
        const int pix = pix0 + wid * 32 + m * 16 + (lane >> 4) * 4 + r;
        Lg[(size_t)pix * 72 + col] = acc[m][n][r] + bias;
      }
  }
}

// ---------------------------------------------------------------------------
// fused softmax+fold body (r5-verified)
// ---------------------------------------------------------------------------
__device__ __forceinline__ void fold_body(
    const int pb, const float* __restrict__ Lg, float* __restrict__ S)
{
  const int p  = pb * 256 + threadIdx.x;
  const int b  = p >> 12;
  const int yx = p & 4095;
  const int y  = yx >> 6, x = yx & 63;

  float s[8];
  #pragma unroll
  for (int h = 0; h < 8; ++h) s[h] = 0.f;

  #pragma unroll
  for (int i = 0; i < 3; ++i){
    const int ys = y + 1 - i;
    if (ys < 0 || ys >= H_) continue;
    #pragma unroll
    for (int j = 0; j < 3; ++j){
      const int xs = x + 1 - j;
      if (xs < 0 || xs >= W_) continue;
      const int pn = (b << 12) + ys * W_ + xs;
      const int k  = i * 3 + j;
      float d[72];
      #pragma unroll
      for (int q = 0; q < 18; ++q)
        *(float4*)&d[q * 4] = *(const float4*)&Lg[(size_t)pn * 72 + q * 4];
      #pragma unroll
      for (int h = 0; h < 8; ++h){
        float mx = d[h * 9];
        #pragma unroll
        for (int kk = 1; kk < 9; ++kk) mx = fmaxf(mx, d[h * 9 + kk]);
        float e[9], sum = 0.f;
        #pragma unroll
        for (int kk = 0; kk < 9; ++kk){
          e[kk] = __expf((d[h * 9 + kk] - mx) * kInvSqrtD);
          sum += e[kk];
        }
        s[h] += e[k] / sum;
      }
    }
  }
  #pragma unroll
  for (int h = 0; h < 8; ++h)
    S[(((size_t)b * HEADS + h) << 12) + yx] = s[h];
}

// ---------------------------------------------------------------------------
// pack_fgbg standalone (r5-verified fast form): grid (256,4)
// ---------------------------------------------------------------------------
__global__ __launch_bounds__(256) void pack_fgbg(
    const float* __restrict__ fg, const float* __restrict__ bg,
    u16* __restrict__ G)
{
  const int t = threadIdx.x;
  const int pix0 = blockIdx.x * 128;
  const int chg  = blockIdx.y * 128 + (t >> 6) * 32;
  const int pix  = pix0 + (t & 63) * 2;
  const int b = pix >> 12, yx = pix & 4095;

  u16 buf0[32], buf1[32];
  #pragma unroll
  for (int i = 0; i < 32; ++i){
    const int c = chg + i;
    const float* src = (c < 256)
        ? &fg[((size_t)b * 256 + c) * HW + yx]
        : &bg[((size_t)b * 256 + (c - 256)) * HW + yx];
    const float2 v = *(const float2*)src;
    buf0[i] = f2bf(v.x);
    buf1[i] = f2bf(v.y);
  }
  #pragma unroll
  for (int i = 0; i < 32; i += 8)
    *(short8*)&G[(size_t)pix * 512 + chg + i] = *(short8*)&buf0[i];
  #pragma unroll
  for (int i = 0; i < 32; i += 8)
    *(short8*)&G[(size_t)(pix + 1) * 512 + chg + i] = *(short8*)&buf1[i];
}

// ---------------------------------------------------------------------------
// pack_all v2: T=9 weight segs now read the FLAT source (coalesced float2,
// 512B/wave) and scatter 2B stores (fire-and-forget) — r19's form read with
// 36B lane stride (~9x TA line-transactions). Mapping unchanged:
// e=(o*C+c)*9+t -> q=e/9, o=q>>lgC, c=q&(C-1); dst[(t*256+o)*C+c].
// segs (blocks): w1 288 | w2 1152 | w3 1152 | w4 1152 | wv 256 | wp 256 |
// wcat 160 | pack_x 128 | xpad-border 65 | slAB-zero 520 = 5129
// ---------------------------------------------------------------------------
__device__ __forceinline__ void packw_flat(const float* __restrict__ src,
    u16* __restrict__ dst, int LGC, int e)
{
  const int q = e / 9;
  const int t = e - q * 9;
  const int o = q >> LGC;
  const int c = q & ((1 << LGC) - 1);
  dst[(((t << 8) + o) << LGC) + c] = f2h(src[e]);
}

__device__ __forceinline__ void packw_seg2(const float* __restrict__ src,
    u16* __restrict__ dst, int LGC, int base)
{
  const float2 v = *(const float2*)&src[base];   // coalesced 8B/lane
  {
    const int e = base, q = e / 9, t = e - q * 9;
    const int o = q >> LGC, c = q & ((1 << LGC) - 1);
    dst[(((t << 8) + o) << LGC) + c] = f2h(v.x);
  }
  {
    const int e = base + 1, q = e / 9, t = e - q * 9;
    const int o = q >> LGC, c = q & ((1 << LGC) - 1);
    dst[(((t << 8) + o) << LGC) + c] = f2h(v.y);
  }
}

__global__ __launch_bounds__(256) void pack_all(
    const float* __restrict__ w1, const float* __restrict__ w2,
    const float* __restrict__ w3, const float* __restrict__ w4,
    const float* __restrict__ Wv, const float* __restrict__ Wp,
    const float* __restrict__ Wfg, const float* __restrict__ Wbg,
    const float* __restrict__ x,
    u16* __restrict__ w1f, u16* __restrict__ w2f, u16* __restrict__ w3f,
    u16* __restrict__ w4f, u16* __restrict__ wvf, u16* __restrict__ wpf,
    u16* __restrict__ wcat, u16* __restrict__ xpad,
    u16* __restrict__ slA, u16* __restrict__ slB)
{
  const int bid = blockIdx.x;
  const int tid = threadIdx.x;

  if (bid < 288){                        // w1: C=64, N=147456, flat-read
    packw_seg2(w1, w1f, 6, (bid * 256 + tid) * 2);
  } else if (bid < 1440){                // w2: C=256, N=589824
    packw_seg2(w2, w2f, 8, ((bid - 288) * 256 + tid) * 2);
  } else if (bid < 2592){                // w3
    packw_seg2(w3, w3f, 8, ((bid - 1440) * 256 + tid) * 2);
  } else if (bid < 3744){                // w4
    packw_seg2(w4, w4f, 8, ((bid - 2592) * 256 + tid) * 2);
  } else if (bid < 4000){                // Wv: T=1 (already coalesced form)
    const int idx = (bid - 3744) * 256 + tid;
    const int c = idx & 255, o = idx >> 8;
    wvf[idx] = f2h(Wv[(size_t)o * 256 + c]);
  } else if (bid < 4256){                // Wp: T=1
    const int idx = (bid - 4000) * 256 + tid;
    const int c = idx & 255, o = idx >> 8;
    wpf[idx] = f2h(Wp[(size_t)o * 256 + c]);
  } else if (bid < 4416){                // wcat[80][512] bf16
    const int idx = (bid - 4256) * 256 + tid;
    const int o = idx >> 9, c = idx & 511;
    float v = 0.f;
    if (o < 72) v = (c < 256) ? Wfg[o * 256 + c] : -Wbg[o * 256 + (c - 256)];
    wcat[idx] = (o < 72) ? f2bf(v) : (u16)0;
  } else if (bid < 4544){                // pack x -> padded pixel-major f16
    const int p = (bid - 4416) * 256 + tid;
    const int b = p >> 12, yx = p & 4095;
    const int y = yx >> 6, xx = yx & 63;
    const size_t pr = ((size_t)b * PADR + (y + 1) * 66 + (xx + 1)) * 64;
    const float* xs = x + (size_t)b * 64 * HW + yx;
    #pragma unroll 8
    for (int c = 0; c < 64; c += 2){
      const u16 h0 = f2h(xs[(size_t)c * HW]);
      const u16 h1 = f2h(xs[(size_t)(c + 1) * HW]);
      *(u32*)&xpad[pr + c] = (u32)h0 | ((u32)h1 << 16);
    }
  } else if (bid < 4609){                // xpad border zero
    const int u = (bid - 4544) * 256 + tid;
    if (u >= 16640) return;
    const int b = u / 2080;
    const int r = u - b * 2080;
    const int pi = r >> 3;
    const int ch = (r & 7) * 8;
    int py, px;
    if (pi < 66){ py = 0; px = pi; }
    else if (pi < 132){ py = 65; px = pi - 66; }
    else { const int k = pi - 132; py = 1 + (k >> 1); px = (k & 1) * 65; }
    const short8 z = {0,0,0,0,0,0,0,0};
    *(short8*)&xpad[((size_t)b * PADR + py * 66 + px) * 64 + ch] = z;
  } else {                               // slA/slB border zero
    int u = (bid - 4609) * 256 + tid;
    u16* base = slA;
    if (u >= 66560){ base = slB; u -= 66560; }
    const int b = u / 8320;
    const int r = u - b * 8320;
    const int pi = r >> 5;
    const int ch = (r & 31) * 8;
    int py, px;
    if (pi < 66){ py = 0; px = pi; }
    else if (pi < 132){ py = 65; px = pi - 66; }
    else { const int k = pi - 132; py = 1 + (k >> 1); px = (k & 1) * 65; }
    const short8 z = {0,0,0,0,0,0,0,0};
    *(short8*)&base[((size_t)b * PADR + py * 66 + px) * 256 + ch] = z;
  }
}

// ---------------------------------------------------------------------------
// L2: attn_gemm (0..255, first — r15/r17 measured-better) ∪ conv1 (256..767)
// ---------------------------------------------------------------------------
__global__ __launch_bounds__(256, 2) void conv1_attn_kernel(
    const u16* __restrict__ xpad, const u16* __restrict__ w1f,
    const float* __restrict__ g1, const float* __restrict__ b1,
    const float* __restrict__ m1, const float* __restrict__ v1,
    u16* __restrict__ slA,
    const u16* __restrict__ G, const u16* __restrict__ wcat,
    const float* __restrict__ bfg, const float* __restrict__ bbg,
    float* __restrict__ Lg)
{
  __shared__ u16 smem[32768];
  const int bid = blockIdx.x;
  if (bid < 256){
    attn_body(smem, bid * 128, G, wcat, bfg, bbg, Lg);
  } else {
    const int cb = bid - 256;
    conv_body<64, 9, 0>(smem, (cb & 255) * 128, (cb >> 8) * 128,
                        xpad, w1f, g1, b1, m1, v1, nullptr,
                        slA, nullptr);
  }
}

// ---------------------------------------------------------------------------
// L3: conv2 (0..511, first — r16/r17 measured-better) ∪ softmax_fold (tail)
// ---------------------------------------------------------------------------
__global__ __launch_bounds__(256, 2) void conv2_fold_kernel(
    const u16* __restrict__ slA, const u16* __restrict__ w2f,
    const float* __restrict__ g2, const float* __restrict__ b2,
    const float* __restrict__ m2, const float* __restrict__ v2,
    u16* __restrict__ slB,
    const float* __restrict__ Lg, float* __restrict__ S)
{
  __shared__ u16 smem[32768];
  const int bid = blockIdx.x;
  if (bid < 512){
    conv_body<256, 9, 0>(smem, (bid & 255) * 128, (bid >> 8) * 128,
                         slA, w2f, g2, b2, m2, v2, nullptr,
                         slB, nullptr);
  } else {
    fold_body(bid - 512, Lg, S);
  }
}

// ---------------------------------------------------------------------------
extern "C" void kernel_launch(void* const* d_in, const int* in_sizes, int n_in,
                              void* d_out, int out_size, void* d_ws, size_t ws_size,
                              hipStream_t stream)
{
  const float* x   = (const float*)d_in[0];
  const float* fg  = (const float*)d_in[1];
  const float* bg  = (const float*)d_in[2];
  const float* w1  = (const float*)d_in[3];
  const float* g1  = (const float*)d_in[4];
  const float* b1  = (const float*)d_in[5];
  const float* m1  = (const float*)d_in[6];
  const float* v1  = (const float*)d_in[7];
  const float* w2  = (const float*)d_in[8];
  const float* g2  = (const float*)d_in[9];
  const float* b2  = (const float*)d_in[10];
  const float* m2  = (const float*)d_in[11];
  const float* v2  = (const float*)d_in[12];
  const float* Wv  = (const float*)d_in[13];
  const float* bv  = (const float*)d_in[14];
  const float* Wfg = (const float*)d_in[15];
  const float* bfg = (const float*)d_in[16];
  const float* Wbg = (const float*)d_in[17];
  const float* bbg = (const float*)d_in[18];
  const float* Wp  = (const float*)d_in[19];
  const float* bp  = (const float*)d_in[20];
  const float* w3  = (const float*)d_in[21];
  const float* g3  = (const float*)d_in[22];
  const float* b3  = (const float*)d_in[23];
  const float* m3  = (const float*)d_in[24];
  const float* v3  = (const float*)d_in[25];
  const float* w4  = (const float*)d_in[26];
  const float* g4  = (const float*)d_in[27];
  const float* b4  = (const float*)d_in[28];
  const float* m4  = (const float*)d_in[29];
  const float* v4  = (const float*)d_in[30];

  const size_t XB = (size_t)BATCH * PADR * 64 * 2;    // 4,460,544
  const size_t PB = (size_t)BATCH * PADR * 256 * 2;   // 17,842,176

  char* p = (char*)d_ws;
  u16* xpad = (u16*)p;             p += XB;
  u16* slA  = (u16*)p;             p += PB;
  u16* slB  = (u16*)p;             p += PB;
  u16* G    = (u16*)p;             p += (size_t)32768 * 512 * 2;  // 33.5MB
  u16* w1f  = (u16*)p; p += 294912;
  u16* w2f  = (u16*)p; p += 1179648;
  u16* w3f  = (u16*)p; p += 1179648;
  u16* w4f  = (u16*)p; p += 1179648;
  u16* wvf  = (u16*)p; p += 131072;
  u16* wpf  = (u16*)p; p += 131072;
  u16* wcat = (u16*)p;             p += 80 * 512 * 2;
  float* S    = (float*)p;         p += (size_t)BATCH * HEADS * HW * 4;
  float* Lg   = (float*)p;         p += (size_t)BATCH * HW * 72 * 4;

  const dim3 blk(256);

  // L0a: pack fg/bg -> G
  pack_fgbg<<<dim3(256, 4), blk, 0, stream>>>(fg, bg, G);

  // L0b: all weight/input packs + borders (flat-read weight segs)
  pack_all<<<dim3(5129), blk, 0, stream>>>(
      w1, w2, w3, w4, Wv, Wp, Wfg, Wbg, x,
      w1f, w2f, w3f, w4f, wvf, wpf, wcat, xpad, slA, slB);

  // L2: attn_gemm ∪ conv1 (attn first)
  conv1_attn_kernel<<<dim3(768), blk, 0, stream>>>(
      xpad, w1f, g1, b1, m1, v1, slA, G, wcat, bfg, bbg, Lg);

  // L3: conv2 ∪ softmax_fold (conv first)
  conv2_fold_kernel<<<dim3(640), blk, 0, stream>>>(
      slA, w2f, g2, b2, m2, v2, slB, Lg, S);

  const dim3 ggrid(256, 2);
  // Wv + S-mul: slB -> slA (u = v*S)
  gemm_conv<256, 1, 1><<<ggrid, blk, 0, stream>>>(
      slB, wvf, bv, nullptr, nullptr, nullptr, S, slA, nullptr);
  // Wp: slA -> slB (o)
  gemm_conv<256, 1, 2><<<ggrid, blk, 0, stream>>>(
      slA, wpf, bp, nullptr, nullptr, nullptr, nullptr, slB, nullptr);
  // conv3: slB -> slA (h3)
  gemm_conv<256, 9, 0><<<ggrid, blk, 0, stream>>>(
      slB, w3f, g3, b3, m3, v3, nullptr, slA, nullptr);
  // conv4: slA -> d_out (f32 channel-major)
  gemm_conv<256, 9, 3><<<ggrid, blk, 0, stream>>>(
      slA, w4f, g4, b4, m4, v4, nullptr, nullptr, (float*)d_out);
}